// Round 2
// baseline (54.408 us; speedup 1.0000x reference)
//
#include <hip/hip_runtime.h>

// Problem constants (from reference setup_inputs)
#define BZ    32
#define NPTS  16384
#define NSMP  4096
#define KNB   64
#define NCH   6
#define RDISC 0.05f

// Layout: block = 64 threads = 1 wave; wave handles 16 samples
// (4 lanes per sample, 16 neighbors per lane). Grid = 131072/16 = 8192 blocks.
// XCD swizzle: XCD x gets contiguous 1024 blocks = 16384 samples = 4 batches
// -> 4 x 393KB feature tables, L2-resident per XCD.
//
// Per row (24B, 8B-aligned): one dwordx4 + one dwordx2 gather (HW needs only
// dword alignment). Cosine denominators via rsq(qs*q) (one transcendental
// instead of 2 sqrt + 1 IEEE div). Cross product is linear in the neighbor
// -> computed once in the epilogue from the unmasked xyz mean.

__global__ __launch_bounds__(64) void pnpp_kernel(
    const float* __restrict__ feat,     // [BZ*NPTS*NCH]
    const int*   __restrict__ nk_idx,   // [BZ*NSMP*KNB]
    const float* __restrict__ nk_dist,  // [BZ*NSMP*KNB]
    const int*   __restrict__ fps_idx,  // [BZ*NSMP]
    float*       __restrict__ out)      // [BZ*NSMP*11]
{
    const int lane = threadIdx.x & 63;
    const int bid  = blockIdx.x;
    // XCD-aware swizzle (grid = 8192, multiple of 8)
    const int work = (bid & 7) * (gridDim.x >> 3) + (bid >> 3); // 0..8191
    const int g = lane >> 2;   // sample within wave (0..15)
    const int j = lane & 3;    // lane within sample (0..3)
    const int s = work * 16 + g;             // sample id 0..131071
    const int b = s >> 12;                   // batch (NSMP = 4096)

    // Sampled point features (uniform within 4-lane group)
    const int p = fps_idx[s];
    const float* fsrow = feat + (long)p * NCH;
    const float4 fa  = *(const float4*)(fsrow);      // 8B-aligned dwordx4: OK on HW
    const float2 fb2 = *(const float2*)(fsrow + 4);
    const float fs0=fa.x, fs1=fa.y, fs2=fa.z, fs3=fa.w, fs4=fb2.x, fs5=fb2.y;
    const float qs1 = fs0*fs0 + fs1*fs1 + fs2*fs2;   // |fs_xyz|^2
    const float qs2 = fs3*fs3 + fs4*fs4 + fs5*fs5;   // |fs_nrm|^2

    const float* fbase = feat + (long)b * (NPTS * NCH);

    float cnt=0.f;
    float s0=0.f,s1=0.f,s2=0.f,s3=0.f,s4=0.f,s5=0.f;   // masked sums
    float m0=0.f,m1=0.f,m2=0.f;                         // unmasked xyz sums (for cross)
    float c1=0.f,c2=0.f;                                // cosine sums

    // idx/dist: lane j, chunk c covers neighbors [c*16 + 4j, c*16 + 4j + 4)
    // -> each 16B load instruction is wave-contiguous (16 samples x 64B).
    const long kb0 = (long)s * KNB + j * 4;
    #pragma unroll
    for (int c = 0; c < 4; ++c) {
        const int4   i4 = *(const int4*)  (nk_idx  + kb0 + c * 16);
        const float4 d4 = *(const float4*)(nk_dist + kb0 + c * 16);
        const int   ridx[4] = {i4.x, i4.y, i4.z, i4.w};
        const float rdst[4] = {d4.x, d4.y, d4.z, d4.w};
        #pragma unroll
        for (int q = 0; q < 4; ++q) {
            const float* fr = fbase + (long)ridx[q] * NCH;
            const float4 fA = *(const float4*)(fr);      // f0..f3 (8B aligned)
            const float2 fB = *(const float2*)(fr + 4);  // f4,f5
            const float f0=fA.x, f1=fA.y, f2=fA.z, f3=fA.w, f4=fB.x, f5=fB.y;

            const float ind = (rdst[q] <= RDISC) ? 1.f : 0.f;
            cnt += ind;
            s0 += ind*f0; s1 += ind*f1; s2 += ind*f2;
            s3 += ind*f3; s4 += ind*f4; s5 += ind*f5;
            m0 += f0; m1 += f1; m2 += f2;

            const float q1 = f0*f0 + f1*f1 + f2*f2;
            const float n1 = fs0*f0 + fs1*f1 + fs2*f2;
            c1 += n1 * __builtin_amdgcn_rsqf(qs1 * q1);

            const float q2 = f3*f3 + f4*f4 + f5*f5;
            const float n2 = fs3*f3 + fs4*f4 + fs5*f5;
            c2 += n2 * __builtin_amdgcn_rsqf(qs2 * q2);
        }
    }

    // Butterfly reduce over the 4-lane group (masks 1,2 stay in-group)
    #pragma unroll
    for (int m = 1; m < 4; m <<= 1) {
        cnt += __shfl_xor(cnt, m, 64);
        s0  += __shfl_xor(s0,  m, 64);
        s1  += __shfl_xor(s1,  m, 64);
        s2  += __shfl_xor(s2,  m, 64);
        s3  += __shfl_xor(s3,  m, 64);
        s4  += __shfl_xor(s4,  m, 64);
        s5  += __shfl_xor(s5,  m, 64);
        m0  += __shfl_xor(m0,  m, 64);
        m1  += __shfl_xor(m1,  m, 64);
        m2  += __shfl_xor(m2,  m, 64);
        c1  += __shfl_xor(c1,  m, 64);
        c2  += __shfl_xor(c2,  m, 64);
    }

    // Finalize (all 4 lanes of a group hold the full sums)
    const float rc = __builtin_amdgcn_rcpf(cnt);
    const float d0 = fs0 - s0*rc, d1 = fs1 - s1*rc, d2 = fs2 - s2*rc;
    const float d3 = fs3 - s3*rc, d4 = fs4 - s4*rc, d5 = fs5 - s5*rc;
    const float ik = 1.f / (float)KNB;
    const float o6 = c1 * ik, o7 = c2 * ik;
    const float mm0 = m0 * ik, mm1 = m1 * ik, mm2 = m2 * ik;
    const float o8  = fs1*mm2 - fs2*mm1;   // cross(fs_xyz, mean_xyz)
    const float o9  = fs2*mm0 - fs0*mm2;
    const float o10 = fs0*mm1 - fs1*mm0;

    // Each lane writes channels j, j+4, j+8 (lane 3 skips the third).
    const float v0 = (j==0) ? d0 : (j==1) ? d1 : (j==2) ? d2 : d3;
    const float v1 = (j==0) ? d4 : (j==1) ? d5 : (j==2) ? o6 : o7;
    const float v2 = (j==0) ? o8 : (j==1) ? o9 : o10;
    float* orow = out + (long)s * 11;
    orow[j]     = v0;
    orow[4 + j] = v1;
    if (j < 3) orow[8 + j] = v2;
}

extern "C" void kernel_launch(void* const* d_in, const int* in_sizes, int n_in,
                              void* d_out, int out_size, void* d_ws, size_t ws_size,
                              hipStream_t stream) {
    const float* feat = (const float*)d_in[0];
    const int*   nki  = (const int*)  d_in[1];
    const float* nkd  = (const float*)d_in[2];
    const int*   fps  = (const int*)  d_in[3];
    float* out = (float*)d_out;

    const int total_samples = BZ * NSMP;        // 131072
    const int blocks = total_samples / 16;      // 8192
    pnpp_kernel<<<dim3(blocks), dim3(64), 0, stream>>>(feat, nki, nkd, fps, out);
}

// Round 3
// 50.821 us; speedup vs baseline: 1.0706x; 1.0706x over previous
//
#include <hip/hip_runtime.h>

// Problem constants (from reference setup_inputs)
#define BZ    32
#define NPTS  16384
#define NSMP  4096
#define KNB   64
#define NCH   6
#define RDISC 0.05f

// Layout: block = 256 threads = 4 waves. Wave handles 8 samples:
//   8 lanes/sample = 4 lane-pairs; each pair handles 16 neighbor rows.
// Pair-gather: ONE dwordx4 per row per pair —
//   even lane loads row*24    -> (f0,f1,f2,f3)
//   odd  lane loads row*24+8  -> (f2,f3,f4,f5)
// Even lane: xyz cosine, masked sums f0..f3, unmasked xyz mean (for cross).
// Odd  lane: nrm cosine (f3,f4,f5), masked sums f4,f5 (in C,D slots).
// Combine: butterfly xor 2,4 (within parity, across the 4 pairs), then one
// xor-1 exchange; every lane computes all 11 outputs; coalesced select-write.
// Grid = 131072/32 = 4096 blocks; XCD swizzle keeps 4 batches (1.6 MB) per XCD L2.

__global__ __launch_bounds__(256) void pnpp_kernel(
    const float* __restrict__ feat,     // [BZ*NPTS*NCH]
    const int*   __restrict__ nk_idx,   // [BZ*NSMP*KNB]
    const float* __restrict__ nk_dist,  // [BZ*NSMP*KNB]
    const int*   __restrict__ fps_idx,  // [BZ*NSMP]
    float*       __restrict__ out)      // [BZ*NSMP*11]
{
    const int lane = threadIdx.x & 63;
    const int wid  = threadIdx.x >> 6;
    const int bid  = blockIdx.x;
    const int work = (bid & 7) * (gridDim.x >> 3) + (bid >> 3); // 0..4095
    const int g      = lane >> 3;  // sample within wave (0..7)
    const int t      = lane & 7;   // lane within sample group (0..7)
    const int h      = t >> 1;     // pair id (0..3)
    const int parity = t & 1;      // 0 = xyz-role, 1 = nrm-role
    const int s = work * 32 + wid * 8 + g;   // sample id 0..131071
    const int b = s >> 12;                   // batch (NSMP = 4096)

    // Sampled point features (uniform within 8-lane group)
    const int p = fps_idx[s];                     // < 524288, *6 fits int
    const float* fsrow = feat + p * NCH;
    const float4 fa  = *(const float4*)(fsrow);
    const float2 fb2 = *(const float2*)(fsrow + 4);
    const float fs0=fa.x, fs1=fa.y, fs2=fa.z, fs3=fa.w, fs4=fb2.x, fs5=fb2.y;
    const float qs1 = fs0*fs0 + fs1*fs1 + fs2*fs2;
    const float qs2 = fs3*fs3 + fs4*fs4 + fs5*fs5;

    // Role-selected cosine reference vector (hoisted)
    const float g0 = parity ? fs3 : fs0;
    const float g1 = parity ? fs4 : fs1;
    const float g2 = parity ? fs5 : fs2;
    const float qsel = parity ? qs2 : qs1;

    // Gather base: odd lanes offset +2 floats into each row
    const float* fbase = feat + b * (NPTS * NCH) + parity * 2;

    float cnt=0.f;
    float A=0.f, B=0.f, C=0.f, D=0.f;      // masked sums of v.x..v.w
    float mx=0.f, my=0.f, mz=0.f;          // unmasked v.x..v.z (even: xyz)
    float cc=0.f;                           // cosine accumulator

    // Pair h covers neighbors [16h, 16h+16); both lanes load the same
    // idx/dist chunks (pair-duplicated addresses, same line footprint).
    const int kb = s * KNB + h * 16;        // s*64 <= 8.4M, fits int
    #pragma unroll
    for (int c = 0; c < 4; ++c) {
        const int4   i4 = *(const int4*)  (nk_idx  + kb + c * 4);
        const float4 d4 = *(const float4*)(nk_dist + kb + c * 4);
        const int   ridx[4] = {i4.x, i4.y, i4.z, i4.w};
        const float rdst[4] = {d4.x, d4.y, d4.z, d4.w};
        #pragma unroll
        for (int q = 0; q < 4; ++q) {
            const float4 v = *(const float4*)(fbase + ridx[q] * NCH);
            // even: v=(f0,f1,f2,f3)   odd: v=(f2,f3,f4,f5)
            const float ind = (rdst[q] <= RDISC) ? 1.f : 0.f;
            cnt += ind;
            A += ind*v.x; B += ind*v.y; C += ind*v.z; D += ind*v.w;
            mx += v.x; my += v.y; mz += v.z;

            const float u  = parity ? v.y : v.x;   // even f0 / odd f3
            const float vv = parity ? v.z : v.y;   // even f1 / odd f4
            const float w  = parity ? v.w : v.z;   // even f2 / odd f5
            const float qq = u*u + vv*vv + w*w;
            const float nn = g0*u + g1*vv + g2*w;
            cc += nn * __builtin_amdgcn_rsqf(qsel * qq);
        }
    }

    // Butterfly over masks 2,4: sums across the 4 pairs, per parity.
    #pragma unroll
    for (int m = 2; m < 8; m <<= 1) {
        cnt += __shfl_xor(cnt, m, 64);
        A   += __shfl_xor(A,   m, 64);
        B   += __shfl_xor(B,   m, 64);
        C   += __shfl_xor(C,   m, 64);
        D   += __shfl_xor(D,   m, 64);
        mx  += __shfl_xor(mx,  m, 64);
        my  += __shfl_xor(my,  m, 64);
        mz  += __shfl_xor(mz,  m, 64);
        cc  += __shfl_xor(cc,  m, 64);
    }
    // Cross-parity exchange (cnt is identical across parity already)
    const float pA  = __shfl_xor(A,  1, 64);
    const float pB  = __shfl_xor(B,  1, 64);
    const float pC  = __shfl_xor(C,  1, 64);
    const float pD  = __shfl_xor(D,  1, 64);
    const float pmx = __shfl_xor(mx, 1, 64);
    const float pmy = __shfl_xor(my, 1, 64);
    const float pmz = __shfl_xor(mz, 1, 64);
    const float pcc = __shfl_xor(cc, 1, 64);

    // Assemble full sums on every lane (even slots: A..D = ind*f0..f3,
    // mx..mz = f0..f2; odd slots: C,D = ind*f4,f5).
    const float s0 = parity ? pA : A;
    const float s1 = parity ? pB : B;
    const float s2 = parity ? pC : C;
    const float s3 = parity ? pD : D;
    const float s4 = parity ? C  : pC;
    const float s5 = parity ? D  : pD;
    const float c1 = parity ? pcc : cc;
    const float c2 = parity ? cc  : pcc;
    const float Mx = parity ? pmx : mx;
    const float My = parity ? pmy : my;
    const float Mz = parity ? pmz : mz;

    const float rc = __builtin_amdgcn_rcpf(cnt);
    const float d0 = fs0 - s0*rc, d1 = fs1 - s1*rc, d2 = fs2 - s2*rc;
    const float d3 = fs3 - s3*rc, d4 = fs4 - s4*rc, d5 = fs5 - s5*rc;
    const float ik = 1.f / (float)KNB;
    const float o6 = c1 * ik, o7 = c2 * ik;
    const float ax = Mx * ik, ay = My * ik, az = Mz * ik;
    const float o8  = fs1*az - fs2*ay;
    const float o9  = fs2*ax - fs0*az;
    const float o10 = fs0*ay - fs1*ax;

    // Lane t writes channel t; lanes 0..2 also write channels 8..10.
    float v0 = d0;
    v0 = (t == 1) ? d1 : v0;
    v0 = (t == 2) ? d2 : v0;
    v0 = (t == 3) ? d3 : v0;
    v0 = (t == 4) ? d4 : v0;
    v0 = (t == 5) ? d5 : v0;
    v0 = (t == 6) ? o6 : v0;
    v0 = (t == 7) ? o7 : v0;
    float v1 = o8;
    v1 = (t == 1) ? o9  : v1;
    v1 = (t == 2) ? o10 : v1;
    float* orow = out + s * 11;
    orow[t] = v0;
    if (t < 3) orow[8 + t] = v1;
}

extern "C" void kernel_launch(void* const* d_in, const int* in_sizes, int n_in,
                              void* d_out, int out_size, void* d_ws, size_t ws_size,
                              hipStream_t stream) {
    const float* feat = (const float*)d_in[0];
    const int*   nki  = (const int*)  d_in[1];
    const float* nkd  = (const float*)d_in[2];
    const int*   fps  = (const int*)  d_in[3];
    float* out = (float*)d_out;

    const int total_samples = BZ * NSMP;        // 131072
    const int blocks = total_samples / 32;      // 4096
    pnpp_kernel<<<dim3(blocks), dim3(256), 0, stream>>>(feat, nki, nkd, fps, out);
}